// Round 1
// baseline (572.230 us; speedup 1.0000x reference)
//
#include <hip/hip_runtime.h>
#include <math.h>

// ---------------------------------------------------------------------------
// 2-layer GAT (H=2 heads, mean over heads), fp32.
// Strategy: build CSR by dst once per call (self-loops implicit), then
// wave-per-node softmax+aggregate with zero atomics.
// ---------------------------------------------------------------------------

#define IN_DIM 128
#define HIDC 64     // per-head channels both layers (HID=OUT=64)
#define HEADS 2
#define FLATC 128   // HEADS*HIDC

__device__ __forceinline__ float lrelu02(float t) {
    return t > 0.f ? t : 0.2f * t;
}

// ---- CSR build ------------------------------------------------------------

__global__ void zero_cnt_kernel(int* __restrict__ cnt, int n) {
    int i = blockIdx.x * blockDim.x + threadIdx.x;
    if (i < n) cnt[i] = 0;
}

__global__ void count_kernel(const int* __restrict__ dst, int* __restrict__ cnt, int e) {
    int i = blockIdx.x * blockDim.x + threadIdx.x;
    if (i < e) atomicAdd(&cnt[dst[i]], 1);
}

__global__ __launch_bounds__(1024) void scan_kernel(const int* __restrict__ cnt,
                                                    int* __restrict__ row_start,
                                                    int* __restrict__ cursor, int n) {
    __shared__ int sums[1024];
    const int t = threadIdx.x;
    const int CH = (n + 1023) / 1024;
    const int beg = t * CH;
    const int end = min(beg + CH, n);
    int s = 0;
    for (int i = beg; i < end; ++i) s += cnt[i];
    sums[t] = s;
    __syncthreads();
    // Hillis-Steele inclusive scan
    for (int off = 1; off < 1024; off <<= 1) {
        int v = (t >= off) ? sums[t - off] : 0;
        __syncthreads();
        sums[t] += v;
        __syncthreads();
    }
    int run = (t == 0) ? 0 : sums[t - 1];
    for (int i = beg; i < end; ++i) {
        row_start[i] = run;
        cursor[i] = run;
        run += cnt[i];
    }
    if (end == n && beg < n) row_start[n] = run;  // == E
}

__global__ void scatter_kernel(const int* __restrict__ src, const int* __restrict__ dst,
                               int* __restrict__ cursor, int* __restrict__ adj, int e) {
    int i = blockIdx.x * blockDim.x + threadIdx.x;
    if (i < e) {
        int d = dst[i];
        int pos = atomicAdd(&cursor[d], 1);
        adj[pos] = src[i];
    }
}

// ---- GEMM: C[n,128] = A[n,K] @ B[K,128] -----------------------------------
// 128x128 tile, 256 threads, 8x8 register blocking.

__global__ __launch_bounds__(256) void gemm128(const float* __restrict__ A,
                                               const float* __restrict__ B,
                                               float* __restrict__ C,
                                               int nrows, int K) {
    __shared__ float As[128][33];
    __shared__ float Bs[32][128];
    const int tid = threadIdx.x;
    const int tx = tid & 15;   // col group: cols tx + 16*c
    const int ty = tid >> 4;   // row group: rows ty*8 + r
    const int row0 = blockIdx.x * 128;

    float acc[8][8];
#pragma unroll
    for (int r = 0; r < 8; ++r)
#pragma unroll
        for (int c = 0; c < 8; ++c) acc[r][c] = 0.f;

    for (int k0 = 0; k0 < K; k0 += 32) {
        // A tile 128x32 (guarded, padded LDS)
#pragma unroll
        for (int i = 0; i < 4; ++i) {
            int idx = tid + i * 256;      // 0..1023 float4 slots
            int r = idx >> 3;             // 8 float4 per row
            int c4 = (idx & 7) * 4;
            float4 v = make_float4(0.f, 0.f, 0.f, 0.f);
            int row = row0 + r;
            if (row < nrows) v = *(const float4*)(A + (size_t)row * K + k0 + c4);
            As[r][c4 + 0] = v.x; As[r][c4 + 1] = v.y;
            As[r][c4 + 2] = v.z; As[r][c4 + 3] = v.w;
        }
        // B tile 32x128
#pragma unroll
        for (int i = 0; i < 4; ++i) {
            int idx = tid + i * 256;
            int r = idx >> 5;             // 32 float4 per row
            int c4 = (idx & 31) * 4;
            float4 v = *(const float4*)(B + (size_t)(k0 + r) * FLATC + c4);
            *(float4*)&Bs[r][c4] = v;
        }
        __syncthreads();
#pragma unroll
        for (int kk = 0; kk < 32; ++kk) {
            float a[8], b[8];
#pragma unroll
            for (int r = 0; r < 8; ++r) a[r] = As[ty * 8 + r][kk];
#pragma unroll
            for (int c = 0; c < 8; ++c) b[c] = Bs[kk][tx + 16 * c];
#pragma unroll
            for (int r = 0; r < 8; ++r)
#pragma unroll
                for (int c = 0; c < 8; ++c) acc[r][c] = fmaf(a[r], b[c], acc[r][c]);
        }
        __syncthreads();
    }
#pragma unroll
    for (int r = 0; r < 8; ++r) {
        int row = row0 + ty * 8 + r;
        if (row < nrows) {
#pragma unroll
            for (int c = 0; c < 8; ++c) C[(size_t)row * FLATC + tx + 16 * c] = acc[r][c];
        }
    }
}

// ---- attention dots: e_src[n,h], e_dst[n,h] = <h[n,h,:], att[h,:]> --------
// one wave per node; lanes 0..31 head0, 32..63 head1 (2 channels per lane)

__global__ __launch_bounds__(256) void attn_dots(const float* __restrict__ h,
                                                 const float* __restrict__ att_s,
                                                 const float* __restrict__ att_d,
                                                 float* __restrict__ es,
                                                 float* __restrict__ ed, int n) {
    int node = blockIdx.x * 4 + (threadIdx.x >> 6);
    if (node >= n) return;
    int lane = threadIdx.x & 63;
    float2 v = *(const float2*)(h + (size_t)node * FLATC + 2 * lane);
    float2 a = *(const float2*)(att_s + 2 * lane);
    float2 b = *(const float2*)(att_d + 2 * lane);
    float ps = v.x * a.x + v.y * a.y;
    float pd = v.x * b.x + v.y * b.y;
#pragma unroll
    for (int off = 1; off < 32; off <<= 1) {
        ps += __shfl_xor(ps, off);
        pd += __shfl_xor(pd, off);
    }
    if ((lane & 31) == 0) {
        int head = lane >> 5;
        es[node * 2 + head] = ps;
        ed[node * 2 + head] = pd;
    }
}

// ---- edge softmax + aggregate: one wave per destination node --------------
// out[n,64] = mean_heads( sum_e alpha_e * h[src_e, head, :] ) + bias  (opt relu)

__global__ __launch_bounds__(256) void edge_agg(const int* __restrict__ row_start,
                                                const int* __restrict__ adj,
                                                const float* __restrict__ h,
                                                const float* __restrict__ es,
                                                const float* __restrict__ ed,
                                                const float* __restrict__ bias,
                                                float* __restrict__ out,
                                                int n, int do_relu) {
    int node = blockIdx.x * 4 + (threadIdx.x >> 6);
    if (node >= n) return;
    const int lane = threadIdx.x & 63;
    const int beg = row_start[node];
    const int end = row_start[node + 1];

    const float ed0 = ed[node * 2 + 0];
    const float ed1 = ed[node * 2 + 1];
    const float eself0 = lrelu02(es[node * 2 + 0] + ed0);
    const float eself1 = lrelu02(es[node * 2 + 1] + ed1);

    // online softmax (max + scaled sum), self edge seeds lane 0
    float m0 = eself0, m1 = eself1;
    float s0 = (lane == 0) ? 1.f : 0.f;
    float s1 = s0;
    for (int j = beg + lane; j < end; j += 64) {
        int sidx = adj[j];
        float e0 = lrelu02(es[sidx * 2 + 0] + ed0);
        float e1 = lrelu02(es[sidx * 2 + 1] + ed1);
        if (e0 > m0) { s0 = s0 * expf(m0 - e0) + 1.f; m0 = e0; }
        else         { s0 += expf(e0 - m0); }
        if (e1 > m1) { s1 = s1 * expf(m1 - e1) + 1.f; m1 = e1; }
        else         { s1 += expf(e1 - m1); }
    }
#pragma unroll
    for (int off = 1; off < 64; off <<= 1) {
        float mo0 = __shfl_xor(m0, off), so0 = __shfl_xor(s0, off);
        float mo1 = __shfl_xor(m1, off), so1 = __shfl_xor(s1, off);
        float mn0 = fmaxf(m0, mo0);
        s0 = s0 * expf(m0 - mn0) + so0 * expf(mo0 - mn0);
        m0 = mn0;
        float mn1 = fmaxf(m1, mo1);
        s1 = s1 * expf(m1 - mn1) + so1 * expf(mo1 - mn1);
        m1 = mn1;
    }

    const int head = lane >> 5;
    const float inv = 1.f / ((head ? s1 : s0) + 1e-16f);
    const float mh = head ? m1 : m0;
    const float edh = head ? ed1 : ed0;

    float2 acc = make_float2(0.f, 0.f);
    {   // self edge
        float e = head ? eself1 : eself0;
        float alpha = expf(e - mh) * inv;
        float2 v = *(const float2*)(h + (size_t)node * FLATC + 2 * lane);
        acc.x = fmaf(alpha, v.x, acc.x);
        acc.y = fmaf(alpha, v.y, acc.y);
    }
    for (int j = beg; j < end; ++j) {
        int sidx = adj[j];
        float e = lrelu02(es[sidx * 2 + head] + edh);
        float alpha = expf(e - mh) * inv;
        float2 v = *(const float2*)(h + (size_t)sidx * FLATC + 2 * lane);
        acc.x = fmaf(alpha, v.x, acc.x);
        acc.y = fmaf(alpha, v.y, acc.y);
    }

    // mean over heads: pair lane l (head0 ch c) with lane l+32 (head1 ch c)
    float ox = 0.5f * (acc.x + __shfl_xor(acc.x, 32));
    float oy = 0.5f * (acc.y + __shfl_xor(acc.y, 32));
    if (lane < 32) {
        int c = 2 * lane;
        ox += bias[c];
        oy += bias[c + 1];
        if (do_relu) { ox = fmaxf(ox, 0.f); oy = fmaxf(oy, 0.f); }
        *(float2*)(out + (size_t)node * 64 + c) = make_float2(ox, oy);
    }
}

// ---------------------------------------------------------------------------

extern "C" void kernel_launch(void* const* d_in, const int* in_sizes, int n_in,
                              void* d_out, int out_size, void* d_ws, size_t ws_size,
                              hipStream_t stream) {
    const float* x   = (const float*)d_in[0];
    const int*   ei  = (const int*)d_in[1];
    const float* W1  = (const float*)d_in[2];
    const float* as1 = (const float*)d_in[3];
    const float* ad1 = (const float*)d_in[4];
    const float* b1  = (const float*)d_in[5];
    const float* W2  = (const float*)d_in[6];
    const float* as2 = (const float*)d_in[7];
    const float* ad2 = (const float*)d_in[8];
    const float* b2  = (const float*)d_in[9];

    const int N_ = in_sizes[0] / IN_DIM;   // 50000
    const int E_ = in_sizes[1] / 2;        // 800000
    const int* src = ei;
    const int* dst = ei + E_;

    // workspace carve (16B aligned)
    auto align16 = [](size_t v) { return (v + 15) & ~(size_t)15; };
    char* p = (char*)d_ws;
    int* cnt       = (int*)p; p += align16((size_t)N_ * 4);
    int* row_start = (int*)p; p += align16((size_t)(N_ + 1) * 4);
    int* cursor    = (int*)p; p += align16((size_t)N_ * 4);
    int* adj       = (int*)p; p += align16((size_t)E_ * 4);
    float* h       = (float*)p; p += align16((size_t)N_ * FLATC * 4);
    float* out1    = (float*)p; p += align16((size_t)N_ * 64 * 4);
    float* es      = (float*)p; p += align16((size_t)N_ * 2 * 4);
    float* ed      = (float*)p; p += align16((size_t)N_ * 2 * 4);
    (void)ws_size; (void)n_in; (void)out_size;

    // --- CSR build (shared by both layers) ---
    zero_cnt_kernel<<<(N_ + 255) / 256, 256, 0, stream>>>(cnt, N_);
    count_kernel<<<(E_ + 255) / 256, 256, 0, stream>>>(dst, cnt, E_);
    scan_kernel<<<1, 1024, 0, stream>>>(cnt, row_start, cursor, N_);
    scatter_kernel<<<(E_ + 255) / 256, 256, 0, stream>>>(src, dst, cursor, adj, E_);

    const int gN4 = (N_ + 3) / 4;

    // --- layer 1 ---
    gemm128<<<(N_ + 127) / 128, 256, 0, stream>>>(x, W1, h, N_, IN_DIM);
    attn_dots<<<gN4, 256, 0, stream>>>(h, as1, ad1, es, ed, N_);
    edge_agg<<<gN4, 256, 0, stream>>>(row_start, adj, h, es, ed, b1, out1, N_, 1);

    // --- layer 2 ---
    gemm128<<<(N_ + 127) / 128, 256, 0, stream>>>(out1, W2, h, N_, 64);
    attn_dots<<<gN4, 256, 0, stream>>>(h, as2, ad2, es, ed, N_);
    edge_agg<<<gN4, 256, 0, stream>>>(row_start, adj, h, es, ed, b2, (float*)d_out, N_, 0);
}

// Round 2
// 466.212 us; speedup vs baseline: 1.2274x; 1.2274x over previous
//
#include <hip/hip_runtime.h>
#include <math.h>

// ---------------------------------------------------------------------------
// 2-layer GAT (H=2 heads, mean over heads), fp32.
// CSR by dst (self-loops at slot 0 of each row), then:
//   softmax_alpha: wave-per-node, computes per-edge alpha once (no redundancy)
//   agg:           wave-per-node, pure gather+FMA with precomputed alpha
// ---------------------------------------------------------------------------

#define IN_DIM 128
#define HEADS 2
#define FLATC 128   // HEADS*64

__device__ __forceinline__ float lrelu02(float t) {
    return t > 0.f ? t : 0.2f * t;
}

// ---- CSR build ------------------------------------------------------------

__global__ void init_cnt(int* __restrict__ cnt, int n) {
    int i = blockIdx.x * blockDim.x + threadIdx.x;
    if (i < n) cnt[i] = 1;   // self loop
}

__global__ void count_kernel(const int* __restrict__ dst, int* __restrict__ cnt, int e) {
    int i = blockIdx.x * blockDim.x + threadIdx.x;
    if (i < e) atomicAdd(&cnt[dst[i]], 1);
}

// hierarchical exclusive scan over cnt -> row_start; self edge written at slot 0
__global__ __launch_bounds__(256) void scan_bsum(const int* __restrict__ cnt,
                                                 int* __restrict__ bsum, int n) {
    __shared__ int red[256];
    int t = threadIdx.x;
    int i = blockIdx.x * 256 + t;
    red[t] = (i < n) ? cnt[i] : 0;
    __syncthreads();
#pragma unroll
    for (int off = 128; off > 0; off >>= 1) {
        if (t < off) red[t] += red[t + off];
        __syncthreads();
    }
    if (t == 0) bsum[blockIdx.x] = red[0];
}

__global__ __launch_bounds__(1024) void scan_boff(const int* __restrict__ bsum,
                                                  int* __restrict__ boff,
                                                  int* __restrict__ row_start,
                                                  int nb, int n) {
    __shared__ int s[1024];
    int t = threadIdx.x;
    int v = (t < nb) ? bsum[t] : 0;
    s[t] = v;
    __syncthreads();
    for (int off = 1; off < 1024; off <<= 1) {
        int u = (t >= off) ? s[t - off] : 0;
        __syncthreads();
        s[t] += u;
        __syncthreads();
    }
    if (t < nb) boff[t] = s[t] - v;
    if (t == nb - 1) row_start[n] = s[t];   // total = E + N
}

__global__ __launch_bounds__(256) void scan_write(const int* __restrict__ cnt,
                                                  const int* __restrict__ boff,
                                                  int* __restrict__ row_start,
                                                  int* __restrict__ cursor,
                                                  int* __restrict__ adj, int n) {
    __shared__ int s[256];
    int t = threadIdx.x;
    int i = blockIdx.x * 256 + t;
    int v = (i < n) ? cnt[i] : 0;
    s[t] = v;
    __syncthreads();
    for (int off = 1; off < 256; off <<= 1) {
        int u = (t >= off) ? s[t - off] : 0;
        __syncthreads();
        s[t] += u;
        __syncthreads();
    }
    if (i < n) {
        int rs = boff[blockIdx.x] + s[t] - v;
        row_start[i] = rs;
        adj[rs] = i;          // self edge at slot 0
        cursor[i] = rs + 1;
    }
}

__global__ void scatter_kernel(const int* __restrict__ src, const int* __restrict__ dst,
                               int* __restrict__ cursor, int* __restrict__ adj, int e) {
    int i = blockIdx.x * blockDim.x + threadIdx.x;
    if (i < e) {
        int d = dst[i];
        int pos = atomicAdd(&cursor[d], 1);
        adj[pos] = src[i];
    }
}

// ---- GEMM: C[n,128] = A[n,K] @ B[K,128] -----------------------------------

__global__ __launch_bounds__(256) void gemm128(const float* __restrict__ A,
                                               const float* __restrict__ B,
                                               float* __restrict__ C,
                                               int nrows, int K) {
    __shared__ float As[128][33];
    __shared__ float Bs[32][128];
    const int tid = threadIdx.x;
    const int tx = tid & 15;
    const int ty = tid >> 4;
    const int row0 = blockIdx.x * 128;

    float acc[8][8];
#pragma unroll
    for (int r = 0; r < 8; ++r)
#pragma unroll
        for (int c = 0; c < 8; ++c) acc[r][c] = 0.f;

    for (int k0 = 0; k0 < K; k0 += 32) {
#pragma unroll
        for (int i = 0; i < 4; ++i) {
            int idx = tid + i * 256;
            int r = idx >> 3;
            int c4 = (idx & 7) * 4;
            float4 v = make_float4(0.f, 0.f, 0.f, 0.f);
            int row = row0 + r;
            if (row < nrows) v = *(const float4*)(A + (size_t)row * K + k0 + c4);
            As[r][c4 + 0] = v.x; As[r][c4 + 1] = v.y;
            As[r][c4 + 2] = v.z; As[r][c4 + 3] = v.w;
        }
#pragma unroll
        for (int i = 0; i < 4; ++i) {
            int idx = tid + i * 256;
            int r = idx >> 5;
            int c4 = (idx & 31) * 4;
            float4 v = *(const float4*)(B + (size_t)(k0 + r) * FLATC + c4);
            *(float4*)&Bs[r][c4] = v;
        }
        __syncthreads();
#pragma unroll
        for (int kk = 0; kk < 32; ++kk) {
            float a[8], b[8];
#pragma unroll
            for (int r = 0; r < 8; ++r) a[r] = As[ty * 8 + r][kk];
#pragma unroll
            for (int c = 0; c < 8; ++c) b[c] = Bs[kk][tx + 16 * c];
#pragma unroll
            for (int r = 0; r < 8; ++r)
#pragma unroll
                for (int c = 0; c < 8; ++c) acc[r][c] = fmaf(a[r], b[c], acc[r][c]);
        }
        __syncthreads();
    }
#pragma unroll
    for (int r = 0; r < 8; ++r) {
        int row = row0 + ty * 8 + r;
        if (row < nrows) {
#pragma unroll
            for (int c = 0; c < 8; ++c) C[(size_t)row * FLATC + tx + 16 * c] = acc[r][c];
        }
    }
}

// ---- attention dots -------------------------------------------------------

__global__ __launch_bounds__(256) void attn_dots(const float* __restrict__ h,
                                                 const float* __restrict__ att_s,
                                                 const float* __restrict__ att_d,
                                                 float* __restrict__ es,
                                                 float* __restrict__ ed, int n) {
    int node = blockIdx.x * 4 + (threadIdx.x >> 6);
    if (node >= n) return;
    int lane = threadIdx.x & 63;
    float2 v = *(const float2*)(h + (size_t)node * FLATC + 2 * lane);
    float2 a = *(const float2*)(att_s + 2 * lane);
    float2 b = *(const float2*)(att_d + 2 * lane);
    float ps = v.x * a.x + v.y * a.y;
    float pd = v.x * b.x + v.y * b.y;
#pragma unroll
    for (int off = 1; off < 32; off <<= 1) {
        ps += __shfl_xor(ps, off);
        pd += __shfl_xor(pd, off);
    }
    if ((lane & 31) == 0) {
        int head = lane >> 5;
        es[node * 2 + head] = ps;
        ed[node * 2 + head] = pd;
    }
}

// ---- softmax + per-edge alpha (wave per node) -----------------------------
// es2[n] = (e_src head0, head1); ed2[n] likewise. alpha2[j] = per-CSR-slot
// alpha for both heads. Self edge is CSR slot 0, so no special casing.

__global__ __launch_bounds__(256) void softmax_alpha(const int* __restrict__ row_start,
                                                     const int* __restrict__ adj,
                                                     const float2* __restrict__ es2,
                                                     const float2* __restrict__ ed2,
                                                     float2* __restrict__ alpha2,
                                                     int n) {
    int node = blockIdx.x * 4 + (threadIdx.x >> 6);
    if (node >= n) return;
    const int lane = threadIdx.x & 63;
    const int beg = row_start[node];
    const int end = row_start[node + 1];
    const float2 edv = ed2[node];

    float e0 = -3.0e38f, e1 = -3.0e38f;       // this lane's first-strip values
    float m0 = -3.0e38f, m1 = -3.0e38f;
    float s0 = 0.f, s1 = 0.f;
    for (int j = beg + lane; j < end; j += 64) {
        float2 ev = es2[adj[j]];
        float f0 = lrelu02(ev.x + edv.x);
        float f1 = lrelu02(ev.y + edv.y);
        if (j < beg + 64) { e0 = f0; e1 = f1; }
        float mn0 = fmaxf(m0, f0);
        s0 = s0 * expf(m0 - mn0) + expf(f0 - mn0);
        m0 = mn0;
        float mn1 = fmaxf(m1, f1);
        s1 = s1 * expf(m1 - mn1) + expf(f1 - mn1);
        m1 = mn1;
    }
#pragma unroll
    for (int off = 1; off < 64; off <<= 1) {
        float mo0 = __shfl_xor(m0, off), so0 = __shfl_xor(s0, off);
        float mo1 = __shfl_xor(m1, off), so1 = __shfl_xor(s1, off);
        float mn0 = fmaxf(m0, mo0);
        s0 = s0 * expf(m0 - mn0) + so0 * expf(mo0 - mn0);
        m0 = mn0;
        float mn1 = fmaxf(m1, mo1);
        s1 = s1 * expf(m1 - mn1) + so1 * expf(mo1 - mn1);
        m1 = mn1;
    }
    const float inv0 = 1.f / (s0 + 1e-16f);
    const float inv1 = 1.f / (s1 + 1e-16f);

    int j0 = beg + lane;
    if (j0 < end)
        alpha2[j0] = make_float2(expf(e0 - m0) * inv0, expf(e1 - m1) * inv1);
    for (int j = j0 + 64; j < end; j += 64) {   // rare: degree > 64
        float2 ev = es2[adj[j]];
        float f0 = lrelu02(ev.x + edv.x);
        float f1 = lrelu02(ev.y + edv.y);
        alpha2[j] = make_float2(expf(f0 - m0) * inv0, expf(f1 - m1) * inv1);
    }
}

// ---- aggregate: out[n,64] = mean_h(sum_j alpha_j * h[adj_j]) + bias -------

__global__ __launch_bounds__(256) void agg(const int* __restrict__ row_start,
                                           const int* __restrict__ adj,
                                           const float* __restrict__ h,
                                           const float2* __restrict__ alpha2,
                                           const float* __restrict__ bias,
                                           float* __restrict__ out,
                                           int n, int do_relu) {
    int node = blockIdx.x * 4 + (threadIdx.x >> 6);
    if (node >= n) return;
    const int lane = threadIdx.x & 63;
    const int head = lane >> 5;
    const int beg = row_start[node];
    const int end = row_start[node + 1];

    float ax = 0.f, ay = 0.f;
    int j = beg;
    for (; j + 4 <= end; j += 4) {
        int i0 = adj[j], i1 = adj[j + 1], i2 = adj[j + 2], i3 = adj[j + 3];
        float2 a0 = alpha2[j], a1 = alpha2[j + 1];
        float2 a2 = alpha2[j + 2], a3 = alpha2[j + 3];
        float2 v0 = *(const float2*)(h + (size_t)i0 * FLATC + 2 * lane);
        float2 v1 = *(const float2*)(h + (size_t)i1 * FLATC + 2 * lane);
        float2 v2 = *(const float2*)(h + (size_t)i2 * FLATC + 2 * lane);
        float2 v3 = *(const float2*)(h + (size_t)i3 * FLATC + 2 * lane);
        float w0 = head ? a0.y : a0.x;
        float w1 = head ? a1.y : a1.x;
        float w2 = head ? a2.y : a2.x;
        float w3 = head ? a3.y : a3.x;
        ax = fmaf(w0, v0.x, ax); ay = fmaf(w0, v0.y, ay);
        ax = fmaf(w1, v1.x, ax); ay = fmaf(w1, v1.y, ay);
        ax = fmaf(w2, v2.x, ax); ay = fmaf(w2, v2.y, ay);
        ax = fmaf(w3, v3.x, ax); ay = fmaf(w3, v3.y, ay);
    }
    for (; j < end; ++j) {
        int i0 = adj[j];
        float2 a0 = alpha2[j];
        float w0 = head ? a0.y : a0.x;
        float2 v0 = *(const float2*)(h + (size_t)i0 * FLATC + 2 * lane);
        ax = fmaf(w0, v0.x, ax); ay = fmaf(w0, v0.y, ay);
    }

    float ox = 0.5f * (ax + __shfl_xor(ax, 32));
    float oy = 0.5f * (ay + __shfl_xor(ay, 32));
    if (lane < 32) {
        int c = 2 * lane;
        ox += bias[c];
        oy += bias[c + 1];
        if (do_relu) { ox = fmaxf(ox, 0.f); oy = fmaxf(oy, 0.f); }
        *(float2*)(out + (size_t)node * 64 + c) = make_float2(ox, oy);
    }
}

// ---------------------------------------------------------------------------

extern "C" void kernel_launch(void* const* d_in, const int* in_sizes, int n_in,
                              void* d_out, int out_size, void* d_ws, size_t ws_size,
                              hipStream_t stream) {
    const float* x   = (const float*)d_in[0];
    const int*   ei  = (const int*)d_in[1];
    const float* W1  = (const float*)d_in[2];
    const float* as1 = (const float*)d_in[3];
    const float* ad1 = (const float*)d_in[4];
    const float* b1  = (const float*)d_in[5];
    const float* W2  = (const float*)d_in[6];
    const float* as2 = (const float*)d_in[7];
    const float* ad2 = (const float*)d_in[8];
    const float* b2  = (const float*)d_in[9];

    const int N_ = in_sizes[0] / IN_DIM;   // 50000
    const int E_ = in_sizes[1] / 2;        // 800000
    const int* src = ei;
    const int* dst = ei + E_;
    const int TOT = E_ + N_;               // CSR slots incl self loops

    auto align16 = [](size_t v) { return (v + 15) & ~(size_t)15; };
    char* p = (char*)d_ws;
    int* cnt       = (int*)p; p += align16((size_t)N_ * 4);
    int* row_start = (int*)p; p += align16((size_t)(N_ + 1) * 4);
    int* cursor    = (int*)p; p += align16((size_t)N_ * 4);
    int* adj       = (int*)p; p += align16((size_t)TOT * 4);
    int* bsum      = (int*)p; p += align16((size_t)1024 * 4);
    int* boff      = (int*)p; p += align16((size_t)1024 * 4);
    float* h       = (float*)p; p += align16((size_t)N_ * FLATC * 4);
    float* out1    = (float*)p; p += align16((size_t)N_ * 64 * 4);
    float* es      = (float*)p; p += align16((size_t)N_ * 2 * 4);
    float* ed      = (float*)p; p += align16((size_t)N_ * 2 * 4);
    float* alpha   = (float*)p; p += align16((size_t)TOT * 2 * 4);
    (void)ws_size; (void)n_in; (void)out_size;

    const int NB = (N_ + 255) / 256;

    // --- CSR build (self-loops at slot 0) ---
    init_cnt<<<NB, 256, 0, stream>>>(cnt, N_);
    count_kernel<<<(E_ + 255) / 256, 256, 0, stream>>>(dst, cnt, E_);
    scan_bsum<<<NB, 256, 0, stream>>>(cnt, bsum, N_);
    scan_boff<<<1, 1024, 0, stream>>>(bsum, boff, row_start, NB, N_);
    scan_write<<<NB, 256, 0, stream>>>(cnt, boff, row_start, cursor, adj, N_);
    scatter_kernel<<<(E_ + 255) / 256, 256, 0, stream>>>(src, dst, cursor, adj, E_);

    const int gN4 = (N_ + 3) / 4;

    // --- layer 1 ---
    gemm128<<<(N_ + 127) / 128, 256, 0, stream>>>(x, W1, h, N_, IN_DIM);
    attn_dots<<<gN4, 256, 0, stream>>>(h, as1, ad1, es, ed, N_);
    softmax_alpha<<<gN4, 256, 0, stream>>>(row_start, adj, (const float2*)es,
                                           (const float2*)ed, (float2*)alpha, N_);
    agg<<<gN4, 256, 0, stream>>>(row_start, adj, h, (const float2*)alpha, b1, out1, N_, 1);

    // --- layer 2 ---
    gemm128<<<(N_ + 127) / 128, 256, 0, stream>>>(out1, W2, h, N_, 64);
    attn_dots<<<gN4, 256, 0, stream>>>(h, as2, ad2, es, ed, N_);
    softmax_alpha<<<gN4, 256, 0, stream>>>(row_start, adj, (const float2*)es,
                                           (const float2*)ed, (float2*)alpha, N_);
    agg<<<gN4, 256, 0, stream>>>(row_start, adj, h, (const float2*)alpha, b2, (float*)d_out, N_, 0);
}

// Round 3
// 453.125 us; speedup vs baseline: 1.2629x; 1.0289x over previous
//
#include <hip/hip_runtime.h>
#include <math.h>

// ---------------------------------------------------------------------------
// 2-layer GAT (H=2 heads, mean over heads), fp32.
// CSR by dst (self-loops at slot 0 of each row), then:
//   softmax_alpha: wave-per-node, single-exp fast path (deg<=64)
//   agg:           wave-per-node, masked 8-wide gather batches for MLP
// ---------------------------------------------------------------------------

#define IN_DIM 128
#define FLATC 128   // HEADS*64

__device__ __forceinline__ float lrelu02(float t) {
    return t > 0.f ? t : 0.2f * t;
}

// ---- CSR build ------------------------------------------------------------

__global__ void count_kernel(const int* __restrict__ dst, int* __restrict__ cnt, int e) {
    int i = blockIdx.x * blockDim.x + threadIdx.x;
    if (i < e) atomicAdd(&cnt[dst[i]], 1);
}

// hierarchical exclusive scan over (cnt+1) -> row_start; self edge at slot 0
__global__ __launch_bounds__(256) void scan_bsum(const int* __restrict__ cnt,
                                                 int* __restrict__ bsum, int n) {
    __shared__ int red[256];
    int t = threadIdx.x;
    int i = blockIdx.x * 256 + t;
    red[t] = (i < n) ? cnt[i] + 1 : 0;
    __syncthreads();
#pragma unroll
    for (int off = 128; off > 0; off >>= 1) {
        if (t < off) red[t] += red[t + off];
        __syncthreads();
    }
    if (t == 0) bsum[blockIdx.x] = red[0];
}

__global__ __launch_bounds__(1024) void scan_boff(const int* __restrict__ bsum,
                                                  int* __restrict__ boff,
                                                  int* __restrict__ row_start,
                                                  int nb, int n) {
    __shared__ int s[1024];
    int t = threadIdx.x;
    int v = (t < nb) ? bsum[t] : 0;
    s[t] = v;
    __syncthreads();
    for (int off = 1; off < 1024; off <<= 1) {
        int u = (t >= off) ? s[t - off] : 0;
        __syncthreads();
        s[t] += u;
        __syncthreads();
    }
    if (t < nb) boff[t] = s[t] - v;
    if (t == nb - 1) row_start[n] = s[t];   // total = E + N
}

__global__ __launch_bounds__(256) void scan_write(const int* __restrict__ cnt,
                                                  const int* __restrict__ boff,
                                                  int* __restrict__ row_start,
                                                  int* __restrict__ cursor,
                                                  int* __restrict__ adj, int n) {
    __shared__ int s[256];
    int t = threadIdx.x;
    int i = blockIdx.x * 256 + t;
    int v = (i < n) ? cnt[i] + 1 : 0;
    s[t] = v;
    __syncthreads();
    for (int off = 1; off < 256; off <<= 1) {
        int u = (t >= off) ? s[t - off] : 0;
        __syncthreads();
        s[t] += u;
        __syncthreads();
    }
    if (i < n) {
        int rs = boff[blockIdx.x] + s[t] - v;
        row_start[i] = rs;
        adj[rs] = i;          // self edge at slot 0
        cursor[i] = rs + 1;
    }
}

__global__ void scatter_kernel(const int* __restrict__ src, const int* __restrict__ dst,
                               int* __restrict__ cursor, int* __restrict__ adj, int e) {
    int i = blockIdx.x * blockDim.x + threadIdx.x;
    if (i < e) {
        int d = dst[i];
        int pos = atomicAdd(&cursor[d], 1);
        adj[pos] = src[i];
    }
}

// ---- GEMM: C[n,128] = A[n,K] @ B[K,128] -----------------------------------

__global__ __launch_bounds__(256) void gemm128(const float* __restrict__ A,
                                               const float* __restrict__ B,
                                               float* __restrict__ C,
                                               int nrows, int K) {
    __shared__ float As[128][33];
    __shared__ float Bs[32][128];
    const int tid = threadIdx.x;
    const int tx = tid & 15;
    const int ty = tid >> 4;
    const int row0 = blockIdx.x * 128;

    float acc[8][8];
#pragma unroll
    for (int r = 0; r < 8; ++r)
#pragma unroll
        for (int c = 0; c < 8; ++c) acc[r][c] = 0.f;

    for (int k0 = 0; k0 < K; k0 += 32) {
#pragma unroll
        for (int i = 0; i < 4; ++i) {
            int idx = tid + i * 256;
            int r = idx >> 3;
            int c4 = (idx & 7) * 4;
            float4 v = make_float4(0.f, 0.f, 0.f, 0.f);
            int row = row0 + r;
            if (row < nrows) v = *(const float4*)(A + (size_t)row * K + k0 + c4);
            As[r][c4 + 0] = v.x; As[r][c4 + 1] = v.y;
            As[r][c4 + 2] = v.z; As[r][c4 + 3] = v.w;
        }
#pragma unroll
        for (int i = 0; i < 4; ++i) {
            int idx = tid + i * 256;
            int r = idx >> 5;
            int c4 = (idx & 31) * 4;
            float4 v = *(const float4*)(B + (size_t)(k0 + r) * FLATC + c4);
            *(float4*)&Bs[r][c4] = v;
        }
        __syncthreads();
#pragma unroll
        for (int kk = 0; kk < 32; ++kk) {
            float a[8], b[8];
#pragma unroll
            for (int r = 0; r < 8; ++r) a[r] = As[ty * 8 + r][kk];
#pragma unroll
            for (int c = 0; c < 8; ++c) b[c] = Bs[kk][tx + 16 * c];
#pragma unroll
            for (int r = 0; r < 8; ++r)
#pragma unroll
                for (int c = 0; c < 8; ++c) acc[r][c] = fmaf(a[r], b[c], acc[r][c]);
        }
        __syncthreads();
    }
#pragma unroll
    for (int r = 0; r < 8; ++r) {
        int row = row0 + ty * 8 + r;
        if (row < nrows) {
#pragma unroll
            for (int c = 0; c < 8; ++c) C[(size_t)row * FLATC + tx + 16 * c] = acc[r][c];
        }
    }
}

// ---- attention dots -------------------------------------------------------

__global__ __launch_bounds__(256) void attn_dots(const float* __restrict__ h,
                                                 const float* __restrict__ att_s,
                                                 const float* __restrict__ att_d,
                                                 float* __restrict__ es,
                                                 float* __restrict__ ed, int n) {
    int node = blockIdx.x * 4 + (threadIdx.x >> 6);
    if (node >= n) return;
    int lane = threadIdx.x & 63;
    float2 v = *(const float2*)(h + (size_t)node * FLATC + 2 * lane);
    float2 a = *(const float2*)(att_s + 2 * lane);
    float2 b = *(const float2*)(att_d + 2 * lane);
    float ps = v.x * a.x + v.y * a.y;
    float pd = v.x * b.x + v.y * b.y;
#pragma unroll
    for (int off = 1; off < 32; off <<= 1) {
        ps += __shfl_xor(ps, off);
        pd += __shfl_xor(pd, off);
    }
    if ((lane & 31) == 0) {
        int head = lane >> 5;
        es[node * 2 + head] = ps;
        ed[node * 2 + head] = pd;
    }
}

// ---- softmax + per-edge alpha (wave per node) -----------------------------
// Fast path (deg<=64): one strip, butterfly max, ONE exp per lane per head.

__global__ __launch_bounds__(256) void softmax_alpha(const int* __restrict__ row_start,
                                                     const int* __restrict__ adj,
                                                     const float2* __restrict__ es2,
                                                     const float2* __restrict__ ed2,
                                                     float2* __restrict__ alpha2,
                                                     int n) {
    int node = blockIdx.x * 4 + (threadIdx.x >> 6);
    if (node >= n) return;
    const int lane = threadIdx.x & 63;
    const int beg = row_start[node];
    const int end = row_start[node + 1];
    const float2 edv = ed2[node];

    if (end - beg <= 64) {
        int j = beg + lane;
        bool act = j < end;
        int id = adj[act ? j : beg];
        float2 ev = es2[id];
        float f0 = lrelu02(ev.x + edv.x);
        float f1 = lrelu02(ev.y + edv.y);
        float m0 = act ? f0 : -3.0e38f;
        float m1 = act ? f1 : -3.0e38f;
#pragma unroll
        for (int off = 1; off < 64; off <<= 1) {
            m0 = fmaxf(m0, __shfl_xor(m0, off));
            m1 = fmaxf(m1, __shfl_xor(m1, off));
        }
        float p0 = act ? expf(f0 - m0) : 0.f;
        float p1 = act ? expf(f1 - m1) : 0.f;
        float s0 = p0, s1 = p1;
#pragma unroll
        for (int off = 1; off < 64; off <<= 1) {
            s0 += __shfl_xor(s0, off);
            s1 += __shfl_xor(s1, off);
        }
        if (act)
            alpha2[j] = make_float2(p0 / (s0 + 1e-16f), p1 / (s1 + 1e-16f));
        return;
    }

    // general path (deg > 64): online softmax across strips
    float m0 = -3.0e38f, m1 = -3.0e38f;
    float s0 = 0.f, s1 = 0.f;
    for (int j = beg + lane; j < end; j += 64) {
        float2 ev = es2[adj[j]];
        float f0 = lrelu02(ev.x + edv.x);
        float f1 = lrelu02(ev.y + edv.y);
        float mn0 = fmaxf(m0, f0);
        s0 = s0 * expf(m0 - mn0) + expf(f0 - mn0);
        m0 = mn0;
        float mn1 = fmaxf(m1, f1);
        s1 = s1 * expf(m1 - mn1) + expf(f1 - mn1);
        m1 = mn1;
    }
#pragma unroll
    for (int off = 1; off < 64; off <<= 1) {
        float mo0 = __shfl_xor(m0, off), so0 = __shfl_xor(s0, off);
        float mo1 = __shfl_xor(m1, off), so1 = __shfl_xor(s1, off);
        float mn0 = fmaxf(m0, mo0);
        s0 = s0 * expf(m0 - mn0) + so0 * expf(mo0 - mn0);
        m0 = mn0;
        float mn1 = fmaxf(m1, mo1);
        s1 = s1 * expf(m1 - mn1) + so1 * expf(mo1 - mn1);
        m1 = mn1;
    }
    const float inv0 = 1.f / (s0 + 1e-16f);
    const float inv1 = 1.f / (s1 + 1e-16f);
    for (int j = beg + lane; j < end; j += 64) {
        float2 ev = es2[adj[j]];
        float f0 = lrelu02(ev.x + edv.x);
        float f1 = lrelu02(ev.y + edv.y);
        alpha2[j] = make_float2(expf(f0 - m0) * inv0, expf(f1 - m1) * inv1);
    }
}

// ---- aggregate: out[n,64] = mean_h(sum_j alpha_j * h[adj_j]) + bias -------
// masked 8-wide batches: 8 adj + 8 alpha + 8 h-gathers in flight per wave.

__global__ __launch_bounds__(256) void agg(const int* __restrict__ row_start,
                                           const int* __restrict__ adj,
                                           const float* __restrict__ h,
                                           const float2* __restrict__ alpha2,
                                           const float* __restrict__ bias,
                                           float* __restrict__ out,
                                           int n, int do_relu) {
    int node = blockIdx.x * 4 + (threadIdx.x >> 6);
    if (node >= n) return;
    const int lane = threadIdx.x & 63;
    const int head = lane >> 5;
    const int beg = row_start[node];
    const int end = row_start[node + 1];
    const float* hp = h + 2 * lane;

    float ax = 0.f, ay = 0.f;
    for (int j = beg; j < end; j += 8) {
        int idx[8];
        float w[8];
#pragma unroll
        for (int k = 0; k < 8; ++k) {
            int jj = j + k;
            int jc = jj < end ? jj : end - 1;
            idx[k] = adj[jc];
            float2 a = alpha2[jc];
            w[k] = (jj < end) ? (head ? a.y : a.x) : 0.f;
        }
        float2 v[8];
#pragma unroll
        for (int k = 0; k < 8; ++k)
            v[k] = *(const float2*)(hp + (size_t)idx[k] * FLATC);
#pragma unroll
        for (int k = 0; k < 8; ++k) {
            ax = fmaf(w[k], v[k].x, ax);
            ay = fmaf(w[k], v[k].y, ay);
        }
    }

    float ox = 0.5f * (ax + __shfl_xor(ax, 32));
    float oy = 0.5f * (ay + __shfl_xor(ay, 32));
    if (lane < 32) {
        int c = 2 * lane;
        ox += bias[c];
        oy += bias[c + 1];
        if (do_relu) { ox = fmaxf(ox, 0.f); oy = fmaxf(oy, 0.f); }
        *(float2*)(out + (size_t)node * 64 + c) = make_float2(ox, oy);
    }
}

// ---------------------------------------------------------------------------

extern "C" void kernel_launch(void* const* d_in, const int* in_sizes, int n_in,
                              void* d_out, int out_size, void* d_ws, size_t ws_size,
                              hipStream_t stream) {
    const float* x   = (const float*)d_in[0];
    const int*   ei  = (const int*)d_in[1];
    const float* W1  = (const float*)d_in[2];
    const float* as1 = (const float*)d_in[3];
    const float* ad1 = (const float*)d_in[4];
    const float* b1  = (const float*)d_in[5];
    const float* W2  = (const float*)d_in[6];
    const float* as2 = (const float*)d_in[7];
    const float* ad2 = (const float*)d_in[8];
    const float* b2  = (const float*)d_in[9];

    const int N_ = in_sizes[0] / IN_DIM;   // 50000
    const int E_ = in_sizes[1] / 2;        // 800000
    const int* src = ei;
    const int* dst = ei + E_;
    const int TOT = E_ + N_;               // CSR slots incl self loops

    auto align16 = [](size_t v) { return (v + 15) & ~(size_t)15; };
    char* p = (char*)d_ws;
    int* cnt       = (int*)p; p += align16((size_t)N_ * 4);
    int* row_start = (int*)p; p += align16((size_t)(N_ + 1) * 4);
    int* cursor    = (int*)p; p += align16((size_t)N_ * 4);
    int* adj       = (int*)p; p += align16((size_t)TOT * 4);
    int* bsum      = (int*)p; p += align16((size_t)1024 * 4);
    int* boff      = (int*)p; p += align16((size_t)1024 * 4);
    float* h       = (float*)p; p += align16((size_t)N_ * FLATC * 4);
    float* out1    = (float*)p; p += align16((size_t)N_ * 64 * 4);
    float* es      = (float*)p; p += align16((size_t)N_ * 2 * 4);
    float* ed      = (float*)p; p += align16((size_t)N_ * 2 * 4);
    float* alpha   = (float*)p; p += align16((size_t)TOT * 2 * 4);
    (void)ws_size; (void)n_in; (void)out_size;

    const int NB = (N_ + 255) / 256;

    // --- CSR build (self-loops at slot 0, +1 folded into scan) ---
    hipMemsetAsync(cnt, 0, (size_t)N_ * 4, stream);
    count_kernel<<<(E_ + 255) / 256, 256, 0, stream>>>(dst, cnt, E_);
    scan_bsum<<<NB, 256, 0, stream>>>(cnt, bsum, N_);
    scan_boff<<<1, 1024, 0, stream>>>(bsum, boff, row_start, NB, N_);
    scan_write<<<NB, 256, 0, stream>>>(cnt, boff, row_start, cursor, adj, N_);
    scatter_kernel<<<(E_ + 255) / 256, 256, 0, stream>>>(src, dst, cursor, adj, E_);

    const int gN4 = (N_ + 3) / 4;

    // --- layer 1 ---
    gemm128<<<(N_ + 127) / 128, 256, 0, stream>>>(x, W1, h, N_, IN_DIM);
    attn_dots<<<gN4, 256, 0, stream>>>(h, as1, ad1, es, ed, N_);
    softmax_alpha<<<gN4, 256, 0, stream>>>(row_start, adj, (const float2*)es,
                                           (const float2*)ed, (float2*)alpha, N_);
    agg<<<gN4, 256, 0, stream>>>(row_start, adj, h, (const float2*)alpha, b1, out1, N_, 1);

    // --- layer 2 ---
    gemm128<<<(N_ + 127) / 128, 256, 0, stream>>>(out1, W2, h, N_, 64);
    attn_dots<<<gN4, 256, 0, stream>>>(h, as2, ad2, es, ed, N_);
    softmax_alpha<<<gN4, 256, 0, stream>>>(row_start, adj, (const float2*)es,
                                           (const float2*)ed, (float2*)alpha, N_);
    agg<<<gN4, 256, 0, stream>>>(row_start, adj, h, (const float2*)alpha, b2, (float*)d_out, N_, 0);
}